// Round 5
// baseline (127.931 us; speedup 1.0000x reference)
//
#include <hip/hip_runtime.h>
#include <hip/hip_bf16.h>

// Single causal attention head. B=4, T=4096, C=1024, H=64, fp32 in/out.
// R4: flash = 2-wave QBLK=32 blocks, K direct from global (no ks LDS),
// defer-max; qkv = per-matrix N-split blocks (grid 256x3).

#define B_DIM 4
#define T_DIM 4096
#define C_DIM 1024
#define H_DIM 64
#define SCALE 0.03125f  // 1/sqrt(1024)
#define KP 72           // LDS stride (elems): 144B rows, 16B-aligned

typedef __attribute__((ext_vector_type(8))) short bf8;    // 8 bf16
typedef __attribute__((ext_vector_type(4))) float f32x4;  // MFMA acc

__device__ __forceinline__ ushort f2bf(float f) {
    union { float f; uint u; } x; x.f = f;
    const uint u = x.u;
    return (ushort)((u + 0x7FFFu + ((u >> 16) & 1u)) >> 16);  // RNE
}
__device__ __forceinline__ uint cvt_pk_bf16(float lo, float hi) {
    uint r;
    asm("v_cvt_pk_bf16_f32 %0, %1, %2" : "=v"(r) : "v"(lo), "v"(hi));
    return r;
}

// ---------------------------------------------------------------------------
// W^T pre-pass: wtg[col][k], col 0..191 = (Wq|Wk|Wv) columns, bf16.
// ---------------------------------------------------------------------------
__global__ __launch_bounds__(256) void wt_kernel(
    const float* __restrict__ Wq, const float* __restrict__ Wk,
    const float* __restrict__ Wv, ushort* __restrict__ wtg)
{
    const int id  = blockIdx.x * 256 + threadIdx.x;  // 24576 total
    const int col = id >> 7;
    const int k8  = (id & 127) * 8;
    const int m   = col >> 6, lc = col & 63;
    const float* W = (m == 0) ? Wq : (m == 1) ? Wk : Wv;
    ushort o[8];
    #pragma unroll
    for (int i = 0; i < 8; ++i)
        o[i] = f2bf(W[(size_t)(k8 + i) * H_DIM + lc]);
    *(bf8*)&wtg[(size_t)col * C_DIM + k8] = *(bf8*)o;
}

// ---------------------------------------------------------------------------
// QKV projection, bf16 MFMA. Grid (256, 3): block = 64 rows x 64 cols of ONE
// matrix (m = blockIdx.y). 4 waves tiled 2x2 (wave = 32x32). Reg-prefetch.
// ---------------------------------------------------------------------------
__global__ __launch_bounds__(256) void qkv_mfma_kernel(
    const float* __restrict__ x, const ushort* __restrict__ wtg,
    ushort* __restrict__ qo, ushort* __restrict__ ko, ushort* __restrict__ vo)
{
    __shared__ ushort xs[64][KP];
    __shared__ ushort wls[64][KP];
    const int t    = threadIdx.x;
    const int lane = t & 63, wave = t >> 6;
    const int g    = lane >> 4, lid = lane & 15;
    const int wr32 = (wave >> 1) * 32, wc32 = (wave & 1) * 32;
    const int m    = blockIdx.y;
    const size_t r0 = (size_t)blockIdx.x * 64;
    ushort* dst = (m == 0) ? qo : (m == 1) ? ko : vo;
    const float sc = (m == 0) ? SCALE : 1.f;
    const ushort* wcol = wtg + (size_t)m * 64 * C_DIM;  // 64 cols x 1024 k

    const int srow = t >> 2, scol = (t & 3) * 16;  // stage coords (64 x 64)

    f32x4 acc[2][2] = {};
    float4 xr[4];
    bf8 wr_[2];

    // prefetch kc=0
    #pragma unroll
    for (int i = 0; i < 4; ++i)
        xr[i] = *(const float4*)&x[(r0 + srow) * C_DIM + scol + i * 4];
    wr_[0] = *(const bf8*)&wcol[(size_t)srow * C_DIM + scol];
    wr_[1] = *(const bf8*)&wcol[(size_t)srow * C_DIM + scol + 8];

    for (int kc = 0; kc < C_DIM / 64; ++kc) {
        __syncthreads();
        {   // write staged regs to LDS (x: fp32 -> bf16)
            uint p[8];
            p[0] = cvt_pk_bf16(xr[0].x, xr[0].y); p[1] = cvt_pk_bf16(xr[0].z, xr[0].w);
            p[2] = cvt_pk_bf16(xr[1].x, xr[1].y); p[3] = cvt_pk_bf16(xr[1].z, xr[1].w);
            p[4] = cvt_pk_bf16(xr[2].x, xr[2].y); p[5] = cvt_pk_bf16(xr[2].z, xr[2].w);
            p[6] = cvt_pk_bf16(xr[3].x, xr[3].y); p[7] = cvt_pk_bf16(xr[3].z, xr[3].w);
            *(bf8*)&xs[srow][scol]     = *(bf8*)&p[0];
            *(bf8*)&xs[srow][scol + 8] = *(bf8*)&p[4];
            *(bf8*)&wls[srow][scol]     = wr_[0];
            *(bf8*)&wls[srow][scol + 8] = wr_[1];
        }
        __syncthreads();
        if (kc + 1 < C_DIM / 64) {  // prefetch next chunk
            const int kb = (kc + 1) * 64;
            #pragma unroll
            for (int i = 0; i < 4; ++i)
                xr[i] = *(const float4*)&x[(r0 + srow) * C_DIM + kb + scol + i * 4];
            wr_[0] = *(const bf8*)&wcol[(size_t)srow * C_DIM + kb + scol];
            wr_[1] = *(const bf8*)&wcol[(size_t)srow * C_DIM + kb + scol + 8];
        }
        #pragma unroll
        for (int ks = 0; ks < 2; ++ks) {
            const bf8 a0 = *(const bf8*)&xs[wr32 + lid][ks * 32 + g * 8];
            const bf8 a1 = *(const bf8*)&xs[wr32 + 16 + lid][ks * 32 + g * 8];
            const bf8 b0 = *(const bf8*)&wls[wc32 + lid][ks * 32 + g * 8];
            const bf8 b1 = *(const bf8*)&wls[wc32 + 16 + lid][ks * 32 + g * 8];
            acc[0][0] = __builtin_amdgcn_mfma_f32_16x16x32_bf16(a0, b0, acc[0][0], 0, 0, 0);
            acc[0][1] = __builtin_amdgcn_mfma_f32_16x16x32_bf16(a0, b1, acc[0][1], 0, 0, 0);
            acc[1][0] = __builtin_amdgcn_mfma_f32_16x16x32_bf16(a1, b0, acc[1][0], 0, 0, 0);
            acc[1][1] = __builtin_amdgcn_mfma_f32_16x16x32_bf16(a1, b1, acc[1][1], 0, 0, 0);
        }
    }

    // epilogue: C map col=lid, row=4g+r (matrix-local cols)
    #pragma unroll
    for (int rt = 0; rt < 2; ++rt)
        #pragma unroll
        for (int ct = 0; ct < 2; ++ct)
            #pragma unroll
            for (int r = 0; r < 4; ++r) {
                const size_t row = r0 + wr32 + rt * 16 + 4 * g + r;
                dst[row * H_DIM + wc32 + ct * 16 + lid] = f2bf(acc[rt][ct][r] * sc);
            }
}

// ---------------------------------------------------------------------------
// Split-K MFMA flash, QBLK=32 (2 waves), K direct from global, V via LDS
// transpose, swapped QK^T (lane-local softmax), defer-max.
// Grid (nslots, 128, 4).
// ---------------------------------------------------------------------------
__global__ __launch_bounds__(128) void flash_mfma_kernel(
    const ushort* __restrict__ q, const ushort* __restrict__ k,
    const ushort* __restrict__ v, float* __restrict__ pO,
    float* __restrict__ pm, float* __restrict__ pl,
    float* __restrict__ out, int S, int nslots, int direct)
{
    const int qt = 127 - blockIdx.y;          // heavy q-tiles first
    const int c  = blockIdx.x;
    const int nkt_total = (qt >> 1) + 1;
    const int kt_begin = c * S;
    const int kt_end   = min((c + 1) * S, nkt_total);
    if (kt_begin >= kt_end) return;           // inactive chunk (block-uniform)

    __shared__ ushort vt[64][KP];             // vt[h][j] = V[j][h]
    __shared__ ushort ps[2][16][KP];          // per-wave P tile: [q-local][k-local]

    const int t    = threadIdx.x;
    const int lane = t & 63, wave = t >> 6;   // wave 0..1
    const int g    = lane >> 4, lid = lane & 15;
    const int b    = blockIdx.z;
    const int bq0  = qt * 32;
    const size_t base = (size_t)b * T_DIM * H_DIM;

    // Q fragment (B-operand): lane (g,lid) holds Q[bq0+wave*16+lid][8g..8g+7]
    const size_t qoff = base + (size_t)(bq0 + wave * 16 + lid) * H_DIM;
    const bf8 qf0 = *(const bf8*)&q[qoff + g * 8];
    const bf8 qf1 = *(const bf8*)&q[qoff + 32 + g * 8];

    f32x4 o_acc[4] = {};                 // O[q=wave*16+4g+r][h=ht*16+lid]
    float m_run = -1e30f, l_run = 0.f;   // per-lane, q = wave*16+lid

    // V prefetch regs: thread owns rows vj..vj+3, cols vc..vc+7
    const int vj = (t & 15) * 4, vc = (t >> 4) * 8;
    bf8 vr[4];
    {
        const int kg = kt_begin * 64;
        #pragma unroll
        for (int i = 0; i < 4; ++i)
            vr[i] = *(const bf8*)&v[base + (size_t)(kg + vj + i) * H_DIM + vc];
    }

    for (int kt64 = kt_begin; kt64 < kt_end; ++kt64) {
        const int kg0 = kt64 * 64;

        // K fragments straight from global (L2-resident) — issue before barriers
        bf8 kf0[4], kf1[4];
        #pragma unroll
        for (int kt = 0; kt < 4; ++kt) {
            const size_t koff = base + (size_t)(kg0 + kt * 16 + lid) * H_DIM;
            kf0[kt] = *(const bf8*)&k[koff + g * 8];
            kf1[kt] = *(const bf8*)&k[koff + 32 + g * 8];
        }

        __syncthreads();                 // prev iter's vt reads done
        #pragma unroll
        for (int i = 0; i < 8; ++i) {    // vt[h=vc+i][j=vj..vj+3]
            uint2 w;
            w.x = (uint)(ushort)vr[0][i] | ((uint)(ushort)vr[1][i] << 16);
            w.y = (uint)(ushort)vr[2][i] | ((uint)(ushort)vr[3][i] << 16);
            *(uint2*)&vt[vc + i][vj] = w;
        }
        __syncthreads();                 // vt ready
        if (kt64 + 1 < kt_end) {         // V prefetch for next tile
            const int kg = (kt64 + 1) * 64;
            #pragma unroll
            for (int i = 0; i < 4; ++i)
                vr[i] = *(const bf8*)&v[base + (size_t)(kg + vj + i) * H_DIM + vc];
        }

        // S^T = mfma(K, Q): lane holds S[q=lid][k = kt*16+4g+r]
        f32x4 st[4];
        #pragma unroll
        for (int kt = 0; kt < 4; ++kt) {
            f32x4 a = {0.f, 0.f, 0.f, 0.f};
            a = __builtin_amdgcn_mfma_f32_16x16x32_bf16(kf0[kt], qf0, a, 0, 0, 0);
            a = __builtin_amdgcn_mfma_f32_16x16x32_bf16(kf1[kt], qf1, a, 0, 0, 0);
            st[kt] = a;
        }

        if (kt64 == (qt >> 1)) {  // diagonal tile: causal mask
            const int qloc = wave * 16 + lid + ((qt & 1) ? 32 : 0);
            #pragma unroll
            for (int kt = 0; kt < 4; ++kt)
                #pragma unroll
                for (int r = 0; r < 4; ++r)
                    if (kt * 16 + 4 * g + r > qloc) st[kt][r] = -1e30f;
        }

        // lane-local online softmax + defer-max (THR=8)
        float mx = fmaxf(fmaxf(fmaxf(st[0][0], st[0][1]), fmaxf(st[0][2], st[0][3])),
                   fmaxf(fmaxf(fmaxf(st[1][0], st[1][1]), fmaxf(st[1][2], st[1][3])),
                   fmaxf(fmaxf(fmaxf(st[2][0], st[2][1]), fmaxf(st[2][2], st[2][3])),
                         fmaxf(fmaxf(st[3][0], st[3][1]), fmaxf(st[3][2], st[3][3])))));
        mx = fmaxf(mx, __shfl_xor(mx, 16));
        mx = fmaxf(mx, __shfl_xor(mx, 32));
        const int nof = (mx <= m_run + 8.0f);        // uniform per row-quad
        const float mnew = nof ? m_run : fmaxf(m_run, mx);
        const float fsc  = nof ? 1.0f : __expf(m_run - mnew);
        m_run = mnew;
        float ls = 0.f;
        #pragma unroll
        for (int kt = 0; kt < 4; ++kt)
            #pragma unroll
            for (int r = 0; r < 4; ++r) {
                const float p = __expf(st[kt][r] - mnew);
                st[kt][r] = p;
                ls += p;
            }
        ls += __shfl_xor(ls, 16);
        ls += __shfl_xor(ls, 32);
        l_run = l_run * fsc + ls;

        // P -> LDS (bf16), per-wave region (no barrier needed)
        #pragma unroll
        for (int kt = 0; kt < 4; ++kt) {
            uint2 w;
            w.x = cvt_pk_bf16(st[kt][0], st[kt][1]);
            w.y = cvt_pk_bf16(st[kt][2], st[kt][3]);
            *(uint2*)&ps[wave][lid][kt * 16 + 4 * g] = w;
        }

        if (!__all(fsc == 1.0f)) {       // rescale O only when some row moved
            float fb[4];
            #pragma unroll
            for (int r = 0; r < 4; ++r) fb[r] = __shfl(fsc, 4 * g + r);
            #pragma unroll
            for (int ht = 0; ht < 4; ++ht)
                #pragma unroll
                for (int r = 0; r < 4; ++r) o_acc[ht][r] *= fb[r];
        }

        // PV: A = P[q=lid][8g..], B = V^T[h=ht*16+lid][8g..]
        const bf8 pa0 = *(const bf8*)&ps[wave][lid][g * 8];
        const bf8 pa1 = *(const bf8*)&ps[wave][lid][32 + g * 8];
        #pragma unroll
        for (int ht = 0; ht < 4; ++ht) {
            const bf8 vb0 = *(const bf8*)&vt[ht * 16 + lid][g * 8];
            const bf8 vb1 = *(const bf8*)&vt[ht * 16 + lid][32 + g * 8];
            o_acc[ht] = __builtin_amdgcn_mfma_f32_16x16x32_bf16(pa0, vb0, o_acc[ht], 0, 0, 0);
            o_acc[ht] = __builtin_amdgcn_mfma_f32_16x16x32_bf16(pa1, vb1, o_acc[ht], 0, 0, 0);
        }
    }

    if (direct) {
        float linv[4];
        #pragma unroll
        for (int r = 0; r < 4; ++r) linv[r] = 1.f / __shfl(l_run, 4 * g + r);
        #pragma unroll
        for (int r = 0; r < 4; ++r) {
            const size_t rowoff = base + (size_t)(bq0 + wave * 16 + 4 * g + r) * H_DIM;
            #pragma unroll
            for (int ht = 0; ht < 4; ++ht)
                out[rowoff + ht * 16 + lid] = o_acc[ht][r] * linv[r];
        }
    } else {
        const size_t u = ((size_t)b * 128 + qt) * nslots + c;
        #pragma unroll
        for (int r = 0; r < 4; ++r) {
            const int row = wave * 16 + 4 * g + r;
            #pragma unroll
            for (int ht = 0; ht < 4; ++ht)
                pO[u * 2048 + (size_t)row * 64 + ht * 16 + lid] = o_acc[ht][r];
        }
        if (g == 0) {
            pm[u * 32 + wave * 16 + lid] = m_run;
            pl[u * 32 + wave * 16 + lid] = l_run;
        }
    }
}

// ---------------------------------------------------------------------------
// Combine partials: out = sum_c O_c * exp(m_c - M) / L.  Grid (128, 4).
// ---------------------------------------------------------------------------
__global__ __launch_bounds__(256) void combine_kernel(
    const float* __restrict__ pO, const float* __restrict__ pm,
    const float* __restrict__ pl, float* __restrict__ out,
    int S, int nslots)
{
    const int qt = blockIdx.x, b = blockIdx.y;
    const int nkt_total = (qt >> 1) + 1;
    const int nch = (nkt_total + S - 1) / S;
    const int t = threadIdx.x;
    const int row = t >> 3, seg = (t & 7) * 8;
    const size_t u0 = ((size_t)b * 128 + qt) * nslots;

    float M = -1e30f;
    for (int c = 0; c < nch; ++c)
        M = fmaxf(M, pm[(u0 + c) * 32 + row]);
    float L = 0.f, alpha[8];
    for (int c = 0; c < nch; ++c) {
        alpha[c] = __expf(pm[(u0 + c) * 32 + row] - M);
        L += pl[(u0 + c) * 32 + row] * alpha[c];
    }
    const float inv = 1.f / L;

    float4 o[2] = {};
    for (int c = 0; c < nch; ++c) {
        const float a = alpha[c];
        #pragma unroll
        for (int j = 0; j < 2; ++j) {
            const float4 p = *(const float4*)&pO[(u0 + c) * 2048 +
                                                 (size_t)row * 64 + seg + j * 4];
            o[j].x += p.x * a; o[j].y += p.y * a;
            o[j].z += p.z * a; o[j].w += p.w * a;
        }
    }
    const size_t ob = (size_t)b * T_DIM * H_DIM + (size_t)(qt * 32 + row) * H_DIM + seg;
    #pragma unroll
    for (int j = 0; j < 2; ++j) {
        float4 r;
        r.x = o[j].x * inv; r.y = o[j].y * inv;
        r.z = o[j].z * inv; r.w = o[j].w * inv;
        *(float4*)&out[ob + j * 4] = r;
    }
}

// ---------------------------------------------------------------------------
extern "C" void kernel_launch(void* const* d_in, const int* in_sizes, int n_in,
                              void* d_out, int out_size, void* d_ws, size_t ws_size,
                              hipStream_t stream)
{
    const float* x  = (const float*)d_in[0];
    const float* Wq = (const float*)d_in[1];
    const float* Wk = (const float*)d_in[2];
    const float* Wv = (const float*)d_in[3];
    float* out = (float*)d_out;

    const size_t MB = 1u << 20;
    char* ws = (char*)d_ws;
    ushort* qb  = (ushort*)(ws);            // 2MB
    ushort* kb  = (ushort*)(ws + 2 * MB);   // 2MB
    ushort* vb  = (ushort*)(ws + 4 * MB);   // 2MB
    ushort* wtg = (ushort*)(ws + 6 * MB);   // 384KB
    float*  pO  = (float*)(ws + 7 * MB);    // nslots*4MB

    int nslots, S;
    if      (ws_size >= 41 * MB) { nslots = 8; S = 8;  }
    else if (ws_size >= 24 * MB) { nslots = 4; S = 16; }
    else if (ws_size >= 16 * MB) { nslots = 2; S = 32; }
    else                         { nslots = 1; S = 64; }
    const int direct = (nslots == 1);
    float* pm = pO + (size_t)nslots * 1048576;  // nslots*64KB
    float* pl = pm + (size_t)nslots * 16384;

    hipLaunchKernelGGL(wt_kernel, dim3(96), dim3(256), 0, stream, Wq, Wk, Wv, wtg);
    hipLaunchKernelGGL(qkv_mfma_kernel, dim3((B_DIM * T_DIM) / 64, 3), dim3(256),
                       0, stream, x, wtg, qb, kb, vb);
    hipLaunchKernelGGL(flash_mfma_kernel, dim3(nslots, 128, B_DIM), dim3(128),
                       0, stream, qb, kb, vb, pO, pm, pl, out, S, nslots, direct);
    if (!direct)
        hipLaunchKernelGGL(combine_kernel, dim3(128, B_DIM), dim3(256),
                           0, stream, pO, pm, pl, out, S, nslots);
}

// Round 7
// 77.159 us; speedup vs baseline: 1.6580x; 1.6580x over previous
//
#include <hip/hip_runtime.h>
#include <hip/hip_bf16.h>

// Single causal attention head. B=4, T=4096, C=1024, H=64, fp32 in/out.
// R6 = R5 with the compile fix: __exp2f -> __builtin_amdgcn_exp2f.
// Flash: R3 structure (QBLK=64, 4 waves, K+V LDS, reg-prefetch) + exp2-domain
// softmax + defer-max. qkv: joint single-x-pass, M=32 blocks.

#define B_DIM 4
#define T_DIM 4096
#define C_DIM 1024
#define H_DIM 64
#define SCALE2 0.0450842066f  // log2(e)/32 : S2 = S * log2(e)
#define KP 72                 // LDS stride (elems): 144B rows, 16B-aligned

typedef __attribute__((ext_vector_type(8))) short bf8;    // 8 bf16
typedef __attribute__((ext_vector_type(4))) float f32x4;  // MFMA acc

__device__ __forceinline__ float fast_exp2(float f) {
    return __builtin_amdgcn_exp2f(f);   // v_exp_f32 (base-2)
}
__device__ __forceinline__ ushort f2bf(float f) {
    union { float f; uint u; } x; x.f = f;
    const uint u = x.u;
    return (ushort)((u + 0x7FFFu + ((u >> 16) & 1u)) >> 16);  // RNE
}
__device__ __forceinline__ uint cvt_pk_bf16(float lo, float hi) {
    uint r;
    asm("v_cvt_pk_bf16_f32 %0, %1, %2" : "=v"(r) : "v"(lo), "v"(hi));
    return r;
}

// ---------------------------------------------------------------------------
// W^T pre-pass: wtg[col][k], col 0..191 = (Wq|Wk|Wv) columns, bf16.
// ---------------------------------------------------------------------------
__global__ __launch_bounds__(256) void wt_kernel(
    const float* __restrict__ Wq, const float* __restrict__ Wk,
    const float* __restrict__ Wv, ushort* __restrict__ wtg)
{
    const int id  = blockIdx.x * 256 + threadIdx.x;  // 24576 total
    const int col = id >> 7;
    const int k8  = (id & 127) * 8;
    const int m   = col >> 6, lc = col & 63;
    const float* W = (m == 0) ? Wq : (m == 1) ? Wk : Wv;
    ushort o[8];
    #pragma unroll
    for (int i = 0; i < 8; ++i)
        o[i] = f2bf(W[(size_t)(k8 + i) * H_DIM + lc]);
    *(bf8*)&wtg[(size_t)col * C_DIM + k8] = *(bf8*)o;
}

// ---------------------------------------------------------------------------
// QKV projection, bf16 MFMA, joint (x read once). Block = 32 rows x 192 cols,
// 4 waves x 3 col-subtiles; K-chunks of 64 with reg-prefetch (T14).
// Grid 512 -> 2 blocks/CU.
// ---------------------------------------------------------------------------
__global__ __launch_bounds__(256) void qkv_mfma_kernel(
    const float* __restrict__ x, const ushort* __restrict__ wtg,
    ushort* __restrict__ qo, ushort* __restrict__ ko, ushort* __restrict__ vo)
{
    __shared__ ushort xs[32][KP];
    __shared__ ushort wts[192][KP];
    const int t    = threadIdx.x;
    const int lane = t & 63, wave = t >> 6;
    const int g    = lane >> 4, lid = lane & 15;
    const size_t r0 = (size_t)blockIdx.x * 32;

    f32x4 acc[2][3] = {};

    const int xrow = t >> 3, xcol = (t & 7) * 8;   // x stage: 32x64, 1 bf8/thr
    float4 xr[2];
    bf8 wreg[6];

    // prefetch kc=0
    xr[0] = *(const float4*)&x[(r0 + xrow) * C_DIM + xcol];
    xr[1] = *(const float4*)&x[(r0 + xrow) * C_DIM + xcol + 4];
    #pragma unroll
    for (int it = 0; it < 6; ++it) {
        const int n = t + it * 256;
        wreg[it] = *(const bf8*)&wtg[(size_t)(n >> 3) * C_DIM + (n & 7) * 8];
    }

    for (int kc = 0; kc < C_DIM / 64; ++kc) {
        __syncthreads();
        {   // write staged regs to LDS (x: fp32 -> bf16)
            uint p[4];
            p[0] = cvt_pk_bf16(xr[0].x, xr[0].y); p[1] = cvt_pk_bf16(xr[0].z, xr[0].w);
            p[2] = cvt_pk_bf16(xr[1].x, xr[1].y); p[3] = cvt_pk_bf16(xr[1].z, xr[1].w);
            *(bf8*)&xs[xrow][xcol] = *(bf8*)p;
            #pragma unroll
            for (int it = 0; it < 6; ++it) {
                const int n = t + it * 256;
                *(bf8*)&wts[n >> 3][(n & 7) * 8] = wreg[it];
            }
        }
        __syncthreads();
        if (kc + 1 < C_DIM / 64) {  // prefetch next chunk
            const int kb = (kc + 1) * 64;
            xr[0] = *(const float4*)&x[(r0 + xrow) * C_DIM + kb + xcol];
            xr[1] = *(const float4*)&x[(r0 + xrow) * C_DIM + kb + xcol + 4];
            #pragma unroll
            for (int it = 0; it < 6; ++it) {
                const int n = t + it * 256;
                wreg[it] = *(const bf8*)&wtg[(size_t)(n >> 3) * C_DIM + kb + (n & 7) * 8];
            }
        }
        #pragma unroll
        for (int ks = 0; ks < 2; ++ks) {
            const bf8 a0 = *(const bf8*)&xs[lid][ks * 32 + g * 8];
            const bf8 a1 = *(const bf8*)&xs[16 + lid][ks * 32 + g * 8];
            #pragma unroll
            for (int j = 0; j < 3; ++j) {
                const int ct = wave * 3 + j;
                const bf8 bb = *(const bf8*)&wts[ct * 16 + lid][ks * 32 + g * 8];
                acc[0][j] = __builtin_amdgcn_mfma_f32_16x16x32_bf16(a0, bb, acc[0][j], 0, 0, 0);
                acc[1][j] = __builtin_amdgcn_mfma_f32_16x16x32_bf16(a1, bb, acc[1][j], 0, 0, 0);
            }
        }
    }

    // epilogue: C map col=lid, row=4g+r. q gets SCALE2 (exp2-domain fold).
    #pragma unroll
    for (int rt = 0; rt < 2; ++rt)
        #pragma unroll
        for (int j = 0; j < 3; ++j) {
            const int ct = wave * 3 + j;
            const int m  = ct >> 2, lc = (ct & 3) * 16 + lid;
            ushort* dst = (m == 0) ? qo : (m == 1) ? ko : vo;
            const float sc = (m == 0) ? SCALE2 : 1.f;
            #pragma unroll
            for (int r = 0; r < 4; ++r) {
                const size_t row = r0 + rt * 16 + 4 * g + r;
                dst[row * H_DIM + lc] = f2bf(acc[rt][j][r] * sc);
            }
        }
}

// ---------------------------------------------------------------------------
// Split-K MFMA flash (R3 structure), swapped QK^T, exp2-domain softmax,
// defer-max. Grid (nslots, 64, 4). Block = 4 waves x 16 q-rows, KBLK=64.
// ---------------------------------------------------------------------------
__global__ __launch_bounds__(256) void flash_mfma_kernel(
    const ushort* __restrict__ q, const ushort* __restrict__ k,
    const ushort* __restrict__ v, float* __restrict__ pO,
    float* __restrict__ pm, float* __restrict__ pl,
    float* __restrict__ out, int S, int nslots, int direct)
{
    const int qt = 63 - blockIdx.y;          // heavy q-tiles first
    const int c  = blockIdx.x;
    const int kt_begin = c * S;
    const int kt_end   = min((c + 1) * S, qt + 1);
    if (kt_begin >= kt_end) return;          // inactive chunk (block-uniform)

    __shared__ ushort ks[64][KP];
    __shared__ ushort vt[64][KP];            // vt[h][j] = V[j][h]
    __shared__ ushort ps[4][16][KP];         // per-wave P tile: [q-local][k-local]

    const int t    = threadIdx.x;
    const int lane = t & 63, wave = t >> 6;
    const int g    = lane >> 4, lid = lane & 15;
    const int b    = blockIdx.z;
    const int bq0  = qt * 64;
    const size_t base = (size_t)b * T_DIM * H_DIM;

    // Q fragment (B-operand): lane (g,lid) holds Q2[bq0+wave*16+lid][8g..8g+7]
    const size_t qoff = base + (size_t)(bq0 + wave * 16 + lid) * H_DIM;
    const bf8 qf0 = *(const bf8*)&q[qoff + g * 8];
    const bf8 qf1 = *(const bf8*)&q[qoff + 32 + g * 8];

    f32x4 o_acc[4] = {};                 // O[q=wave*16+4g+r][h=ht*16+lid]
    float m_run = -1e30f, l_run = 0.f;   // per-lane, q-row = wave*16+lid (log2 dom)

    // reg-prefetch first tile (T14)
    const int krow = t >> 3, kcol = (t & 7) * 8;
    const int vj = (t & 31) * 2, vc = (t >> 5) * 8;
    bf8 kr0, kr1, vr0, vr1;
    {
        const int kg = kt_begin * 64;
        kr0 = *(const bf8*)&k[base + (size_t)(kg + krow) * H_DIM + kcol];
        kr1 = *(const bf8*)&k[base + (size_t)(kg + 32 + krow) * H_DIM + kcol];
        vr0 = *(const bf8*)&v[base + (size_t)(kg + vj) * H_DIM + vc];
        vr1 = *(const bf8*)&v[base + (size_t)(kg + vj + 1) * H_DIM + vc];
    }

    for (int kt64 = kt_begin; kt64 < kt_end; ++kt64) {
        __syncthreads();                 // prev tile LDS reads done
        *(bf8*)&ks[krow][kcol]      = kr0;
        *(bf8*)&ks[32 + krow][kcol] = kr1;
        #pragma unroll
        for (int i = 0; i < 8; ++i) {
            const uint pk = (uint)(ushort)vr0[i] | ((uint)(ushort)vr1[i] << 16);
            *(uint*)&vt[vc + i][vj] = pk;
        }
        __syncthreads();                 // tile ready
        if (kt64 + 1 < kt_end) {         // prefetch next tile under compute
            const int kg = (kt64 + 1) * 64;
            kr0 = *(const bf8*)&k[base + (size_t)(kg + krow) * H_DIM + kcol];
            kr1 = *(const bf8*)&k[base + (size_t)(kg + 32 + krow) * H_DIM + kcol];
            vr0 = *(const bf8*)&v[base + (size_t)(kg + vj) * H_DIM + vc];
            vr1 = *(const bf8*)&v[base + (size_t)(kg + vj + 1) * H_DIM + vc];
        }

        // S2^T = mfma(K, Q2): lane holds S2[q=lid][k = kt*16+4g+r]
        f32x4 st[4];
        #pragma unroll
        for (int kt = 0; kt < 4; ++kt) {
            const bf8 kf0 = *(const bf8*)&ks[kt * 16 + lid][g * 8];
            const bf8 kf1 = *(const bf8*)&ks[kt * 16 + lid][32 + g * 8];
            f32x4 a = {0.f, 0.f, 0.f, 0.f};
            a = __builtin_amdgcn_mfma_f32_16x16x32_bf16(kf0, qf0, a, 0, 0, 0);
            a = __builtin_amdgcn_mfma_f32_16x16x32_bf16(kf1, qf1, a, 0, 0, 0);
            st[kt] = a;
        }

        if (kt64 == qt) {  // diagonal tile: causal mask (kg0 == bq0)
            const int qloc = wave * 16 + lid;
            #pragma unroll
            for (int kt = 0; kt < 4; ++kt)
                #pragma unroll
                for (int r = 0; r < 4; ++r)
                    if (kt * 16 + 4 * g + r > qloc) st[kt][r] = -1e30f;
        }

        // lane-local online softmax, log2 domain, defer-max THR=8
        float mx = fmaxf(fmaxf(fmaxf(st[0][0], st[0][1]), fmaxf(st[0][2], st[0][3])),
                   fmaxf(fmaxf(fmaxf(st[1][0], st[1][1]), fmaxf(st[1][2], st[1][3])),
                   fmaxf(fmaxf(fmaxf(st[2][0], st[2][1]), fmaxf(st[2][2], st[2][3])),
                         fmaxf(fmaxf(st[3][0], st[3][1]), fmaxf(st[3][2], st[3][3])))));
        mx = fmaxf(mx, __shfl_xor(mx, 16));
        mx = fmaxf(mx, __shfl_xor(mx, 32));
        const bool nof = (mx <= m_run + 8.0f);
        const float mnew = nof ? m_run : mx;
        const float fsc  = nof ? 1.0f : fast_exp2(m_run - mnew);
        m_run = mnew;
        float ls = 0.f;
        #pragma unroll
        for (int kt = 0; kt < 4; ++kt)
            #pragma unroll
            for (int r = 0; r < 4; ++r) {
                const float p = fast_exp2(st[kt][r] - mnew);
                st[kt][r] = p;
                ls += p;
            }
        ls += __shfl_xor(ls, 16);
        ls += __shfl_xor(ls, 32);
        l_run = l_run * fsc + ls;

        // P -> LDS (bf16), per-wave region (no barrier needed)
        #pragma unroll
        for (int kt = 0; kt < 4; ++kt) {
            uint2 w;
            w.x = cvt_pk_bf16(st[kt][0], st[kt][1]);
            w.y = cvt_pk_bf16(st[kt][2], st[kt][3]);
            *(uint2*)&ps[wave][lid][kt * 16 + 4 * g] = w;
        }

        if (!__all(nof)) {               // rescale O only when some row moved
            float fb[4];
            #pragma unroll
            for (int r = 0; r < 4; ++r) fb[r] = __shfl(fsc, 4 * g + r);
            #pragma unroll
            for (int ht = 0; ht < 4; ++ht)
                #pragma unroll
                for (int r = 0; r < 4; ++r) o_acc[ht][r] *= fb[r];
        }

        // PV: A = P[q=lid][8g..], B = V^T[h=ht*16+lid][8g..]
        const bf8 pa0 = *(const bf8*)&ps[wave][lid][g * 8];
        const bf8 pa1 = *(const bf8*)&ps[wave][lid][32 + g * 8];
        #pragma unroll
        for (int ht = 0; ht < 4; ++ht) {
            const bf8 vb0 = *(const bf8*)&vt[ht * 16 + lid][g * 8];
            const bf8 vb1 = *(const bf8*)&vt[ht * 16 + lid][32 + g * 8];
            o_acc[ht] = __builtin_amdgcn_mfma_f32_16x16x32_bf16(pa0, vb0, o_acc[ht], 0, 0, 0);
            o_acc[ht] = __builtin_amdgcn_mfma_f32_16x16x32_bf16(pa1, vb1, o_acc[ht], 0, 0, 0);
        }
    }

    if (direct) {
        float linv[4];
        #pragma unroll
        for (int r = 0; r < 4; ++r) linv[r] = 1.f / __shfl(l_run, 4 * g + r);
        #pragma unroll
        for (int r = 0; r < 4; ++r) {
            const size_t rowoff = base + (size_t)(bq0 + wave * 16 + 4 * g + r) * H_DIM;
            #pragma unroll
            for (int ht = 0; ht < 4; ++ht)
                out[rowoff + ht * 16 + lid] = o_acc[ht][r] * linv[r];
        }
    } else {
        const size_t u = ((size_t)b * 64 + qt) * nslots + c;
        #pragma unroll
        for (int r = 0; r < 4; ++r) {
            const int row = wave * 16 + 4 * g + r;
            #pragma unroll
            for (int ht = 0; ht < 4; ++ht)
                pO[u * 4096 + (size_t)row * 64 + ht * 16 + lid] = o_acc[ht][r];
        }
        if (g == 0) {
            pm[u * 64 + wave * 16 + lid] = m_run;   // log2 domain
            pl[u * 64 + wave * 16 + lid] = l_run;
        }
    }
}

// ---------------------------------------------------------------------------
// Combine partials (log2 domain): out = sum_c O_c * 2^(m_c - M) / L.
// ---------------------------------------------------------------------------
__global__ __launch_bounds__(256) void combine_kernel(
    const float* __restrict__ pO, const float* __restrict__ pm,
    const float* __restrict__ pl, float* __restrict__ out,
    int S, int nslots)
{
    const int qt = blockIdx.x, b = blockIdx.y;
    const int nch = min(nslots, (qt + S) / S);
    const int t = threadIdx.x;
    const int row = t >> 2, seg = (t & 3) * 16;
    const size_t u0 = ((size_t)b * 64 + qt) * nslots;

    float M = -1e30f;
    for (int c = 0; c < nch; ++c)
        M = fmaxf(M, pm[(u0 + c) * 64 + row]);
    float L = 0.f, alpha[8];
    for (int c = 0; c < nch; ++c) {
        alpha[c] = fast_exp2(pm[(u0 + c) * 64 + row] - M);
        L += pl[(u0 + c) * 64 + row] * alpha[c];
    }
    const float inv = 1.f / L;

    float4 o[4] = {};
    for (int c = 0; c < nch; ++c) {
        const float a = alpha[c];
        #pragma unroll
        for (int j = 0; j < 4; ++j) {
            const float4 p = *(const float4*)&pO[(u0 + c) * 4096 +
                                                 (size_t)row * 64 + seg + j * 4];
            o[j].x += p.x * a; o[j].y += p.y * a;
            o[j].z += p.z * a; o[j].w += p.w * a;
        }
    }
    const size_t ob = (size_t)b * T_DIM * H_DIM + (size_t)(qt * 64 + row) * H_DIM + seg;
    #pragma unroll
    for (int j = 0; j < 4; ++j) {
        float4 r;
        r.x = o[j].x * inv; r.y = o[j].y * inv;
        r.z = o[j].z * inv; r.w = o[j].w * inv;
        *(float4*)&out[ob + j * 4] = r;
    }
}

// ---------------------------------------------------------------------------
extern "C" void kernel_launch(void* const* d_in, const int* in_sizes, int n_in,
                              void* d_out, int out_size, void* d_ws, size_t ws_size,
                              hipStream_t stream)
{
    const float* x  = (const float*)d_in[0];
    const float* Wq = (const float*)d_in[1];
    const float* Wk = (const float*)d_in[2];
    const float* Wv = (const float*)d_in[3];
    float* out = (float*)d_out;

    const size_t MB = 1u << 20;
    char* ws = (char*)d_ws;
    ushort* qb  = (ushort*)(ws);            // 2MB
    ushort* kb  = (ushort*)(ws + 2 * MB);   // 2MB
    ushort* vb  = (ushort*)(ws + 4 * MB);   // 2MB
    ushort* wtg = (ushort*)(ws + 6 * MB);   // 384KB
    float*  pO  = (float*)(ws + 7 * MB);    // nslots*4MB

    int nslots, S;
    if      (ws_size >= 41 * MB) { nslots = 8; S = 8;  }
    else if (ws_size >= 24 * MB) { nslots = 4; S = 16; }
    else if (ws_size >= 16 * MB) { nslots = 2; S = 32; }
    else                         { nslots = 1; S = 64; }
    const int direct = (nslots == 1);
    float* pm = pO + (size_t)nslots * 1048576;  // nslots*64KB
    float* pl = pm + (size_t)nslots * 16384;

    hipLaunchKernelGGL(wt_kernel, dim3(96), dim3(256), 0, stream, Wq, Wk, Wv, wtg);
    hipLaunchKernelGGL(qkv_mfma_kernel, dim3((B_DIM * T_DIM) / 32), dim3(256),
                       0, stream, x, wtg, qb, kb, vb);
    hipLaunchKernelGGL(flash_mfma_kernel, dim3(nslots, 64, B_DIM), dim3(256),
                       0, stream, qb, kb, vb, pO, pm, pl, out, S, nslots, direct);
    if (!direct)
        hipLaunchKernelGGL(combine_kernel, dim3(64, B_DIM), dim3(256),
                           0, stream, pO, pm, pl, out, S, nslots);
}